// Round 1
// 920.504 us; speedup vs baseline: 1.0991x; 1.0991x over previous
//
#include <hip/hip_runtime.h>

// ---------------------------------------------------------------------------
// MobileViTBlockv2 — fused-chain bf16 MFMA version.
// B=32, C=128, H=W=64, D=256, FF=512, NL=2, PH=PW=2
// p: (B, D, 4, 1024) fp32. Attention chain (v->relu*ctx->out) and FFN chain
// (f1->lrelu->f2) each fused into ONE kernel: phase 1 builds the full
// intermediate for an n-col tile in LDS (MFMA B-fragment order), phase 2
// consumes it from LDS and accumulates into p.
//
// R1 change: k_fused latency-bound fix.
//  - n-tile 64 -> 32 cols: Frag LDS halves (FFN 38 KB total) -> 4 blocks/CU.
//  - double-buffered Alds + float2 register prefetch of next K-chunk:
//    ONE barrier per chunk, global-load latency hidden under MFMA.
// ---------------------------------------------------------------------------

typedef short  bh8 __attribute__((ext_vector_type(8)));   // 8 bf16 = 4 VGPR
typedef float  f4  __attribute__((ext_vector_type(4)));   // MFMA acc
typedef unsigned short us2 __attribute__((ext_vector_type(2)));
typedef unsigned short us4 __attribute__((ext_vector_type(4)));

constexpr int Bc = 32, Cc = 128, Dc = 256, FFc = 512;
constexpr int NNc = 1024, Sc = 4096;
constexpr float EPSc = 1e-5f;

enum SrcMode { S_LNF32, S_BF16 };
enum OutMode { O_STOREF32, O_FOLDBN };

__device__ __forceinline__ unsigned short f2bf(float f) {
  union { float f; unsigned int u; } v; v.f = f;
  unsigned int u = v.u + 0x7FFFu + ((v.u >> 16) & 1u);
  return (unsigned short)(u >> 16);
}

// ---- weight fp32 -> bf16 MFMA A-fragment order ----------------------------
// (m,k) -> ((kt*(M/16)+mt)*64 + lane)*8 + j ; lane=((k>>3)&3)<<4|(m&15), j=k&7
__global__ __launch_bounds__(256) void k_wconv(
    const float* __restrict__ w, unsigned short* __restrict__ dst,
    int total, int klog2)
{
  int idx = blockIdx.x * 256 + threadIdx.x;
  if (idx >= total) return;
  int K = 1 << klog2;
  int m = idx >> klog2, k = idx & (K - 1);
  int Mt = total >> klog2;
  size_t a = ((size_t)((k >> 5) * (Mt >> 4) + (m >> 4)) * 64
              + (((k >> 3) & 3) << 4) + (m & 15)) * 8 + (k & 7);
  dst[a] = f2bf(w[idx]);
}

// ---- dwconv 3x3 + BN1 + lrelu, 4 pixels/thread, bf16 patch layout ---------
__global__ __launch_bounds__(256) void k_dwconv(
    const float* __restrict__ x, const float* __restrict__ dww,
    const float* __restrict__ g, const float* __restrict__ bb,
    const float* __restrict__ mm, const float* __restrict__ vv,
    unsigned short* __restrict__ y1)
{
  int idx = blockIdx.x * 256 + threadIdx.x;   // (b,c,h,w4)
  int w4 = (idx & 15) * 4;
  int h  = (idx >> 4) & 63;
  int c  = (idx >> 10) & 127;
  int bi = idx >> 17;
  const float* xb = x + (size_t)(bi * 128 + c) * Sc;
  const float* wp = dww + c * 9;
  float acc[4] = {0.f, 0.f, 0.f, 0.f};
  #pragma unroll
  for (int kh = 0; kh < 3; ++kh) {
    int rr = h + kh - 1;
    if (rr < 0 || rr > 63) continue;
    const float* row = xb + rr * 64;
    float4 m4 = *reinterpret_cast<const float4*>(row + w4);
    float v[6];
    v[0] = (w4 > 0)  ? row[w4 - 1] : 0.f;
    v[1] = m4.x; v[2] = m4.y; v[3] = m4.z; v[4] = m4.w;
    v[5] = (w4 < 60) ? row[w4 + 4] : 0.f;
    float w0 = wp[kh * 3], w1 = wp[kh * 3 + 1], w2 = wp[kh * 3 + 2];
    #pragma unroll
    for (int o = 0; o < 4; ++o)
      acc[o] += w0 * v[o] + w1 * v[o + 1] + w2 * v[o + 2];
  }
  float sc = g[c] * rsqrtf(vv[c] + EPSc);
  float sh = bb[c] - mm[c] * sc;
  unsigned short r[4];
  #pragma unroll
  for (int o = 0; o < 4; ++o) {
    float val = acc[o] * sc + sh;
    r[o] = f2bf(val > 0.f ? val : 0.1f * val);
  }
  int ph = h & 1;
  size_t base = (size_t)(bi * 128 + c) * Sc + (h >> 1) * 32 + (w4 >> 1);
  *reinterpret_cast<us2*>(y1 + base + (ph * 2 + 0) * NNc) = (us2){r[0], r[2]};
  *reinterpret_cast<us2*>(y1 + base + (ph * 2 + 1) * NNc) = (us2){r[1], r[3]};
}

// ---- LN stats over D, optionally fused q-dot ------------------------------
template<bool QD>
__global__ __launch_bounds__(256) void k_lnstats(
    const float* __restrict__ p, const float* __restrict__ wgq,
    float* __restrict__ mean_, float* __restrict__ rstd_, float* __restrict__ qdot)
{
  __shared__ float wg_s[256];
  int t = threadIdx.x;
  if (QD) { wg_s[t] = wgq[t]; __syncthreads(); }
  int pos = blockIdx.x * 256 + t;
  int b = pos >> 12, s = pos & 4095;
  const float* base = p + (size_t)b * Dc * Sc + s;
  float sum = 0.f, sq = 0.f, qa = 0.f;
  for (int d = 0; d < Dc; ++d) {
    float v = base[(size_t)d * Sc];
    sum += v; sq += v * v;
    if (QD) qa += v * wg_s[d];
  }
  float m   = sum * (1.f / Dc);
  float var = sq * (1.f / Dc) - m * m;
  mean_[pos] = m;
  rstd_[pos] = rsqrtf(fmaxf(var, 0.f) + EPSc);
  if (QD) qdot[pos] = qa;
}

// ---- per-layer prep: wgq = wq*g, s1 = sum(wq*g), s2 = sum(wq*b)+bq --------
__global__ void k_prep(const float* __restrict__ wq, const float* __restrict__ lng,
                       const float* __restrict__ lnb, const float* __restrict__ qb,
                       float* __restrict__ wgq, float* __restrict__ scal)
{
  int t = threadIdx.x, lane = t & 63, wv = t >> 6;
  float w = wq[t];
  float a = w * lng[t], c2 = w * lnb[t];
  wgq[t] = a;
  __shared__ float ra[4], rb[4];
  #pragma unroll
  for (int off = 32; off > 0; off >>= 1) { a += __shfl_xor(a, off); c2 += __shfl_xor(c2, off); }
  if (lane == 0) { ra[wv] = a; rb[wv] = c2; }
  __syncthreads();
  if (t == 0) {
    scal[0] = ra[0] + ra[1] + ra[2] + ra[3];
    scal[1] = rb[0] + rb[1] + rb[2] + rb[3] + qb[0];
  }
}

// ---- softmax over N from qdot/stats; emits u[n]=rs*s and U=sum(m*u) -------
__global__ __launch_bounds__(256) void k_softmax2(
    const float* __restrict__ qdot, const float* __restrict__ mean_,
    const float* __restrict__ rstd_, const float* __restrict__ scal,
    float* __restrict__ ub, float* __restrict__ Ub)
{
  int bp = blockIdx.x, b = bp >> 2, pp = bp & 3;
  int t = threadIdx.x, lane = t & 63, wv = t >> 6;
  __shared__ float r3[4], r4[4];
  float s1 = scal[0], s2 = scal[1];
  int pos0 = b * Sc + pp * NNc;
  float q[4], m_r[4], rs_r[4];
  float mx = -3.4e38f;
  #pragma unroll
  for (int i = 0; i < 4; ++i) {
    int pos = pos0 + t + i * 256;
    m_r[i] = mean_[pos]; rs_r[i] = rstd_[pos];
    q[i] = rs_r[i] * qdot[pos] - m_r[i] * rs_r[i] * s1 + s2;
    mx = fmaxf(mx, q[i]);
  }
  #pragma unroll
  for (int off = 32; off > 0; off >>= 1) mx = fmaxf(mx, __shfl_xor(mx, off));
  if (lane == 0) r3[wv] = mx;
  __syncthreads();
  mx = fmaxf(fmaxf(r3[0], r3[1]), fmaxf(r3[2], r3[3]));
  float sum = 0.f;
  #pragma unroll
  for (int i = 0; i < 4; ++i) { q[i] = __expf(q[i] - mx); sum += q[i]; }
  #pragma unroll
  for (int off = 32; off > 0; off >>= 1) sum += __shfl_xor(sum, off);
  if (lane == 0) r4[wv] = sum;
  __syncthreads();
  float inv = 1.f / (r4[0] + r4[1] + r4[2] + r4[3]);
  float pU = 0.f;
  #pragma unroll
  for (int i = 0; i < 4; ++i) {
    float un = rs_r[i] * q[i] * inv;
    ub[(size_t)bp * NNc + t + i * 256] = un;
    pU += m_r[i] * un;
  }
  #pragma unroll
  for (int off = 32; off > 0; off >>= 1) pU += __shfl_xor(pU, off);
  if (lane == 0) r3[wv] = pU;
  __syncthreads();
  if (t == 0) Ub[bp] = r3[0] + r3[1] + r3[2] + r3[3];
}

// ---- t_c = g_c*(sum_n p[c,n]*u[n] - U) + b_c ------------------------------
__global__ __launch_bounds__(256) void k_tpass(
    const float* __restrict__ p, const float* __restrict__ ub,
    const float* __restrict__ Ub, const float* __restrict__ lng,
    const float* __restrict__ lnb, float* __restrict__ tb)
{
  int cs = blockIdx.x, pp = blockIdx.y, b = blockIdx.z;
  int bp = b * 4 + pp;
  int t = threadIdx.x, lane = t & 63, wv = t >> 6;
  __shared__ float u_s[1024];
  for (int i = t; i < 1024; i += 256) u_s[i] = ub[(size_t)bp * NNc + i];
  __syncthreads();
  float U = Ub[bp];
  const float* pb = p + (size_t)b * Dc * Sc + pp * NNc;
  for (int i = 0; i < 16; ++i) {
    int c = cs * 64 + wv * 16 + i;
    const float* row = pb + (size_t)c * Sc;
    float sm = 0.f;
    #pragma unroll
    for (int j = 0; j < 16; ++j) { int n = lane + 64 * j; sm += row[n] * u_s[n]; }
    #pragma unroll
    for (int off = 32; off > 0; off >>= 1) sm += __shfl_xor(sm, off);
    if (lane == 0) tb[(size_t)bp * Dc + c] = lng[c] * (sm - U) + lnb[c];
  }
}

// ---- ctx[b,d,pp] = wk_row_d . t[b,pp,:] + bk_d ----------------------------
__global__ __launch_bounds__(256) void k_ctx2(
    const float* __restrict__ tb, const float* __restrict__ wk,
    const float* __restrict__ bk, float* __restrict__ ctxb)
{
  int b = blockIdx.x, d = threadIdx.x;
  __shared__ float ts[4][256];
  for (int i = threadIdx.x; i < 1024; i += 256) ts[i >> 8][i & 255] = tb[(size_t)b * 1024 + i];
  __syncthreads();
  const float* wrow = wk + (size_t)d * 256;
  float bkd = bk[d];
  float accp[4] = {0.f, 0.f, 0.f, 0.f};
  for (int c = 0; c < 256; c += 4) {
    float4 wv = *reinterpret_cast<const float4*>(wrow + c);
    #pragma unroll
    for (int pp = 0; pp < 4; ++pp)
      accp[pp] += wv.x * ts[pp][c] + wv.y * ts[pp][c + 1]
                + wv.z * ts[pp][c + 2] + wv.w * ts[pp][c + 3];
  }
  #pragma unroll
  for (int pp = 0; pp < 4; ++pp)
    ctxb[((size_t)(b * 256 + d)) * 4 + pp] = accp[pp] + bkd;
}

__global__ void k_bn2pre(const float* __restrict__ g, const float* __restrict__ bb,
                         const float* __restrict__ mm, const float* __restrict__ vv,
                         float* __restrict__ sc, float* __restrict__ sh)
{
  int c = threadIdx.x;
  if (c < Cc) {
    float s = g[c] * rsqrtf(vv[c] + EPSc);
    sc[c] = s;
    sh[c] = bb[c] - mm[c] * s;
  }
}

// ---------------------------------------------------------------------------
// Fused chain kernel: one (b, pp, 32-col n-tile) per block, 4 waves.
// Phase 1: I = act(W1 @ LN(p) + b1) [* ctx if ATTN], full M1 rows, K=256.
//          Staging is double-buffered with a 1-chunk register prefetch
//          (float2 loads): ONE barrier per K-chunk, load latency hidden
//          under the previous chunk's MFMA.
// Phase 2: p += W2 @ I + b2   (M2=256, K=M1), I read from LDS.
// LDS: FFN ~38 KB (4 blocks/CU), attn ~23 KB.
// ---------------------------------------------------------------------------
template<int M1, bool ATTN>
__global__ __launch_bounds__(256) void k_fused(
    const float* __restrict__ p,
    const float* __restrict__ mean_, const float* __restrict__ rstd_,
    const float* __restrict__ lng, const float* __restrict__ lnb,
    const unsigned short* __restrict__ wf1, const float* __restrict__ b1,
    const float* __restrict__ ctxp,
    const unsigned short* __restrict__ wf2, const float* __restrict__ b2,
    float* __restrict__ dst)
{
  constexpr int NT = 32;                 // n-tile columns
  constexpr int NF = NT / 16;            // B fragments per tile (=2)
  constexpr int ACC1 = M1 / 64;          // row-tiles per wave, phase 1
  int t = threadIdx.x;
  int wv = t >> 6, lane = t & 63;
  int q = lane >> 4, ln16 = lane & 15;
  int nt = blockIdx.x, pp = blockIdx.y, b = blockIdx.z;
  int n0 = nt * NT;

  __shared__ unsigned int Alds[2][NT * 20];       // 5 KB double-buffered staging
  __shared__ unsigned short Frag[M1 * NT];        // intermediate, B-frag order
  __shared__ float m_s[NT], rs_s[NT];
  __shared__ float ctx_s[ATTN ? 256 : 4];

  // staging assignment: thread -> (k-pair kp_s, col-pair n2_s)
  int kp_s = t >> 4;            // 0..15
  int n2_s = (t & 15) * 2;      // 0,2,...,30

  size_t pbase = (size_t)b * Dc * Sc + pp * NNc + n0;

  // prefetch chunk 0 into registers (float2 = 8 B/lane, coalesced per k-row)
  float2 c0 = *reinterpret_cast<const float2*>(p + pbase + (size_t)(kp_s * 2) * Sc + n2_s);
  float2 c1 = *reinterpret_cast<const float2*>(p + pbase + (size_t)(kp_s * 2 + 1) * Sc + n2_s);

  if (t < NT) {
    int pos = b * Sc + pp * NNc + n0 + t;
    m_s[t]  = mean_[pos];
    rs_s[t] = rstd_[pos];
  }
  if (ATTN) ctx_s[t] = ctxp[(size_t)(b * Dc + t) * 4 + pp];

  f4 acc[ACC1][NF];
  #pragma unroll
  for (int i = 0; i < ACC1; ++i)
    #pragma unroll
    for (int j = 0; j < NF; ++j) acc[i][j] = (f4){0.f, 0.f, 0.f, 0.f};

  __syncthreads();   // m_s/rs_s (and ctx_s) ready

  // ---- phase 1: I = W1 @ LN(p), one barrier per K-chunk ----
  for (int kc = 0; kc < 256; kc += 32) {
    // LN + bf16-pack the chunk held in registers
    int k0 = kc + kp_s * 2;
    float g0 = lng[k0], g1 = lng[k0 + 1];
    float h0 = lnb[k0], h1 = lnb[k0 + 1];
    float ms0 = m_s[n2_s],     rs0 = rs_s[n2_s];
    float ms1 = m_s[n2_s + 1], rs1 = rs_s[n2_s + 1];
    float a00 = (c0.x - ms0) * rs0 * g0 + h0;   // (k0  , n2_s  )
    float a01 = (c0.y - ms1) * rs1 * g0 + h0;   // (k0  , n2_s+1)
    float a10 = (c1.x - ms0) * rs0 * g1 + h1;   // (k0+1, n2_s  )
    float a11 = (c1.y - ms1) * rs1 * g1 + h1;   // (k0+1, n2_s+1)
    unsigned int pk0 = (unsigned int)f2bf(a00) | ((unsigned int)f2bf(a10) << 16);
    unsigned int pk1 = (unsigned int)f2bf(a01) | ((unsigned int)f2bf(a11) << 16);

    // issue prefetch of next chunk (registers free after the pack above)
    if (kc < 224) {
      c0 = *reinterpret_cast<const float2*>(p + pbase + (size_t)(kc + 32 + kp_s * 2) * Sc + n2_s);
      c1 = *reinterpret_cast<const float2*>(p + pbase + (size_t)(kc + 32 + kp_s * 2 + 1) * Sc + n2_s);
    }

    unsigned int* alw = Alds[(kc >> 5) & 1];
    alw[n2_s * 20 + kp_s]       = pk0;
    alw[(n2_s + 1) * 20 + kp_s] = pk1;

    bh8 aw[ACC1];
    #pragma unroll
    for (int tm = 0; tm < ACC1; ++tm)
      aw[tm] = *(const bh8*)(wf1 + ((size_t)((kc >> 5) * (M1 >> 4) + wv * ACC1 + tm) * 64 + lane) * 8);

    __syncthreads();   // stage of this chunk visible; dbuf makes 2nd barrier unnecessary

    const unsigned short* al = (const unsigned short*)Alds[(kc >> 5) & 1];
    #pragma unroll
    for (int tn = 0; tn < NF; ++tn) {
      bh8 bwf = *(const bh8*)(al + (tn * 16 + ln16) * 40 + q * 8);
      #pragma unroll
      for (int tm = 0; tm < ACC1; ++tm)
        acc[tm][tn] = __builtin_amdgcn_mfma_f32_16x16x32_bf16(aw[tm], bwf, acc[tm][tn], 0, 0, 0);
    }
  }

  // ---- phase 1 epilogue: act + write Frag (B-frag order) ----
  #pragma unroll
  for (int tm = 0; tm < ACC1; ++tm) {
    int row0 = wv * (M1 / 4) + tm * 16 + q * 4;
    float bia[4], cxv[4];
    #pragma unroll
    for (int r = 0; r < 4; ++r) {
      bia[r] = b1[row0 + r];
      if (ATTN) cxv[r] = ctx_s[row0 + r];
    }
    int kt  = row0 >> 5;
    int sub = (row0 >> 3) & 3;
    int jo  = row0 & 7;
    #pragma unroll
    for (int tn = 0; tn < NF; ++tn) {
      int cl = tn * 16 + ln16;
      us4 pk;
      #pragma unroll
      for (int r = 0; r < 4; ++r) {
        float v = acc[tm][tn][r] + bia[r];
        if (ATTN) v = fmaxf(v, 0.f) * cxv[r];
        else      v = v > 0.f ? v : 0.1f * v;
        pk[r] = f2bf(v);
      }
      *reinterpret_cast<us4*>(Frag + (((kt * NF + (cl >> 4)) * 64 + (sub << 4 | (cl & 15))) * 8 + jo)) = pk;
    }
  }
  __syncthreads();

  // ---- phase 2: p += W2 @ I ----
  f4 acc2[4][NF];
  #pragma unroll
  for (int i = 0; i < 4; ++i)
    #pragma unroll
    for (int j = 0; j < NF; ++j) acc2[i][j] = (f4){0.f, 0.f, 0.f, 0.f};

  for (int kc = 0; kc < M1; kc += 32) {
    bh8 aw2[4];
    #pragma unroll
    for (int tm = 0; tm < 4; ++tm)
      aw2[tm] = *(const bh8*)(wf2 + ((size_t)((kc >> 5) * 16 + wv * 4 + tm) * 64 + lane) * 8);
    #pragma unroll
    for (int tn = 0; tn < NF; ++tn) {
      bh8 bwf = *(const bh8*)(Frag + ((kc >> 5) * NF + tn) * 512 + lane * 8);
      #pragma unroll
      for (int tm = 0; tm < 4; ++tm)
        acc2[tm][tn] = __builtin_amdgcn_mfma_f32_16x16x32_bf16(aw2[tm], bwf, acc2[tm][tn], 0, 0, 0);
    }
  }

  #pragma unroll
  for (int tm = 0; tm < 4; ++tm) {
    #pragma unroll
    for (int r = 0; r < 4; ++r) {
      int row = wv * 64 + tm * 16 + q * 4 + r;
      float bv = b2[row];
      #pragma unroll
      for (int tn = 0; tn < NF; ++tn) {
        int col = n0 + tn * 16 + ln16;
        size_t da = (size_t)(b * Dc + row) * Sc + pp * NNc + col;
        dst[da] += acc2[tm][tn][r] + bv;
      }
    }
  }
}

// ---------------------------------------------------------------------------
// Standalone MFMA GEMM (used for c1 and proj). Same as R4.
// ---------------------------------------------------------------------------
template<int KTOT, int MTOT, int SRCCH, int SSTR, bool SPP,
         SrcMode SM, OutMode OM>
__global__ __launch_bounds__(256) void k_mm(
    const void* __restrict__ src,
    const float* __restrict__ mean_, const float* __restrict__ rstd_,
    const float* __restrict__ lng, const float* __restrict__ lnb,
    const unsigned short* __restrict__ wf, const float* __restrict__ bias,
    const float* __restrict__ bnsc, const float* __restrict__ bnsh,
    void* __restrict__ dst)
{
  int t = threadIdx.x;
  int wv = t >> 6, lane = t & 63;
  int wm = wv & 1, wn = wv >> 1;
  int q = lane >> 4, ln16 = lane & 15;
  int nb = blockIdx.x, b = blockIdx.z;
  int pp = blockIdx.y & 3, mb = blockIdx.y >> 2;
  int n0  = nb * 128;
  int MB0 = mb * 128;

  __shared__ unsigned int Alds[128 * 20];
  __shared__ float m_s[128], rs_s[128];

  if (SM == S_LNF32 && t < 128) {
    int pos = b * Sc + pp * NNc + n0 + t;
    m_s[t]  = mean_[pos];
    rs_s[t] = rstd_[pos];
  }

  f4 acc[4][4];
  #pragma unroll
  for (int i = 0; i < 4; ++i)
    #pragma unroll
    for (int j = 0; j < 4; ++j) acc[i][j] = (f4){0.f, 0.f, 0.f, 0.f};

  size_t sbase = (size_t)b * SRCCH * SSTR + pp * NNc + n0;
  int mtb = (MB0 >> 4) + wm * 4;

  for (int kc = 0; kc < KTOT; kc += 32) {
    bh8 aw[4];
    #pragma unroll
    for (int tm = 0; tm < 4; ++tm)
      aw[tm] = *(const bh8*)(wf + ((size_t)((kc >> 5) * (MTOT >> 4) + mtb + tm) * 64 + lane) * 8);
    __syncthreads();
    #pragma unroll
    for (int it = 0; it < 8; ++it) {
      int n_l = (t & 63) + (it & 1) * 64;
      int kp  = (t >> 6) + (it >> 1) * 4;
      int k0  = kc + kp * 2;
      unsigned int pk;
      if (SM == S_LNF32) {
        const float* sp = (const float*)src;
        float a0 = sp[sbase + (size_t)k0 * SSTR + n_l];
        float a1 = sp[sbase + (size_t)(k0 + 1) * SSTR + n_l];
        float ms = m_s[n_l], rs = rs_s[n_l];
        a0 = (a0 - ms) * rs * lng[k0] + lnb[k0];
        a1 = (a1 - ms) * rs * lng[k0 + 1] + lnb[k0 + 1];
        pk = (unsigned int)f2bf(a0) | ((unsigned int)f2bf(a1) << 16);
      } else {
        const unsigned short* sp = (const unsigned short*)src;
        unsigned int u0 = sp[sbase + (size_t)k0 * SSTR + n_l];
        unsigned int u1 = sp[sbase + (size_t)(k0 + 1) * SSTR + n_l];
        pk = u0 | (u1 << 16);
      }
      Alds[n_l * 20 + kp] = pk;
    }
    __syncthreads();
    const unsigned short* al = (const unsigned short*)Alds;
    #pragma unroll
    for (int tn = 0; tn < 4; ++tn) {
      int nrow = wn * 64 + tn * 16 + ln16;
      bh8 bwf = *(const bh8*)(al + nrow * 40 + q * 8);
      #pragma unroll
      for (int tm = 0; tm < 4; ++tm)
        acc[tm][tn] = __builtin_amdgcn_mfma_f32_16x16x32_bf16(aw[tm], bwf, acc[tm][tn], 0, 0, 0);
    }
  }

  #pragma unroll
  for (int tm = 0; tm < 4; ++tm) {
    #pragma unroll
    for (int r = 0; r < 4; ++r) {
      int row = MB0 + wm * 64 + tm * 16 + q * 4 + r;
      float scv = 0.f, shv = 0.f, bv = 0.f;
      if (OM == O_FOLDBN) { scv = bnsc[row]; shv = bnsh[row]; }
      else                { bv = bias[row]; }
      #pragma unroll
      for (int tn = 0; tn < 4; ++tn) {
        int col = n0 + wn * 64 + tn * 16 + ln16;
        float v = acc[tm][tn][r];
        if (OM == O_FOLDBN) {
          int hh = 2 * (col >> 5) + (pp >> 1), ww = 2 * (col & 31) + (pp & 1);
          ((float*)dst)[((size_t)(b * Cc + row)) * Sc + hh * 64 + ww] = v * scv + shv;
        } else {
          ((float*)dst)[(size_t)(b * MTOT + row) * Sc + pp * NNc + col] = v + bv;
        }
      }
    }
  }
}

// ---------------------------------------------------------------------------
extern "C" void kernel_launch(void* const* d_in, const int* in_sizes, int n_in,
                              void* d_out, int out_size, void* d_ws, size_t ws_size,
                              hipStream_t stream)
{
  const float* x     = (const float*)d_in[0];
  const float* dw_w  = (const float*)d_in[1];
  const float* bn1_g = (const float*)d_in[2];
  const float* bn1_b = (const float*)d_in[3];
  const float* bn1_m = (const float*)d_in[4];
  const float* bn1_v = (const float*)d_in[5];
  const float* c1_w  = (const float*)d_in[6];
  const float* c1_b  = (const float*)d_in[7];
  const float* ln1_g = (const float*)d_in[8];
  const float* ln1_b = (const float*)d_in[9];
  const float* qkv_w = (const float*)d_in[10];
  const float* qkv_b = (const float*)d_in[11];
  const float* out_w = (const float*)d_in[12];
  const float* out_b = (const float*)d_in[13];
  const float* ln2_g = (const float*)d_in[14];
  const float* ln2_b = (const float*)d_in[15];
  const float* f1_w  = (const float*)d_in[16];
  const float* f1_b  = (const float*)d_in[17];
  const float* f2_w  = (const float*)d_in[18];
  const float* f2_b  = (const float*)d_in[19];
  const float* lnf_g = (const float*)d_in[20];
  const float* lnf_b = (const float*)d_in[21];
  const float* projw = (const float*)d_in[22];
  const float* bn2_g = (const float*)d_in[23];
  const float* bn2_b = (const float*)d_in[24];
  const float* bn2_m = (const float*)d_in[25];
  const float* bn2_v = (const float*)d_in[26];
  float* out = (float*)d_out;

  // ---- workspace (~172 MB) ----
  float* ws    = (float*)d_ws;
  float* p     = ws;                                       // 33,554,432 f
  float* reg   = p + (size_t)33554432;                     // 8,388,608 f (y1 bf16)
  unsigned short* y1u = (unsigned short*)reg;
  float* meanb = reg   + (size_t)8388608;
  float* rstdb = meanb + 131072;
  float* qdotb = rstdb + 131072;
  float* ub    = qdotb + 131072;
  float* Ub    = ub    + 131072;                           // 128
  float* tb    = Ub    + 128;                              // 32768
  float* ctxb  = tb    + 32768;                            // 32768
  float* wgq   = ctxb  + 32768;                            // 256
  float* scal  = wgq   + 256;                              // 16
  float* bnscb = scal  + 16;                               // 128
  float* bnshb = bnscb + 128;                              // 128
  unsigned short* wfb = (unsigned short*)(bnshb + 128);
  unsigned short* wf_c1   = wfb;                           // 32768
  unsigned short* wf_v0   = wfb + 32768;                   // per-l stride 393216
  unsigned short* wf_proj = wfb + 32768 + 2 * 393216;      // 32768

  // ---- weight conversion ----
  k_wconv<<<128, 256, 0, stream>>>(c1_w, wf_c1, 256 * 128, 7);
  for (int l = 0; l < 2; ++l) {
    const float* wvp = qkv_w + ((size_t)l * 513 + 257) * Dc;
    unsigned short* base = wf_v0 + (size_t)l * 393216;
    k_wconv<<<256, 256, 0, stream>>>(wvp, base, 256 * 256, 8);
    k_wconv<<<256, 256, 0, stream>>>(out_w + (size_t)l * Dc * Dc, base + 65536, 256 * 256, 8);
    k_wconv<<<512, 256, 0, stream>>>(f1_w + (size_t)l * FFc * Dc, base + 131072, 512 * 256, 8);
    k_wconv<<<512, 256, 0, stream>>>(f2_w + (size_t)l * Dc * FFc, base + 262144, 256 * 512, 9);
  }
  k_wconv<<<128, 256, 0, stream>>>(projw, wf_proj, 128 * 256, 8);

  // ---- 1) dwconv + BN1 + lrelu -> y1 bf16 (patch layout) ----
  k_dwconv<<<16384, 256, 0, stream>>>(x, dw_w, bn1_g, bn1_b, bn1_m, bn1_v, y1u);

  // ---- 2) c1: p = W_c1 @ y1 + b ----
  k_mm<128, 256, 128, 4096, true, S_BF16, O_STOREF32>
      <<<dim3(8, 8, 32), 256, 0, stream>>>(
      y1u, nullptr, nullptr, nullptr, nullptr, wf_c1, c1_b, nullptr, nullptr, p);

  for (int l = 0; l < 2; ++l) {
    const float* g1 = ln1_g + l * Dc; const float* b1 = ln1_b + l * Dc;
    const float* g2 = ln2_g + l * Dc; const float* b2 = ln2_b + l * Dc;
    const float* wq = qkv_w + (size_t)l * 513 * Dc;
    const float* wk = qkv_w + ((size_t)l * 513 + 1) * Dc;
    const float* bq = qkv_b + l * 513;
    const float* bk = qkv_b + l * 513 + 1;
    const float* bvv = qkv_b + l * 513 + 257;
    unsigned short* wbase = wf_v0 + (size_t)l * 393216;

    k_prep<<<1, 256, 0, stream>>>(wq, g1, b1, bq, wgq, scal);
    k_lnstats<true><<<512, 256, 0, stream>>>(p, wgq, meanb, rstdb, qdotb);
    k_softmax2<<<128, 256, 0, stream>>>(qdotb, meanb, rstdb, scal, ub, Ub);
    k_tpass<<<dim3(4, 4, 32), 256, 0, stream>>>(p, ub, Ub, g1, b1, tb);
    k_ctx2<<<32, 256, 0, stream>>>(tb, wk, bk, ctxb);

    // fused attention: p += W_out @ (relu(W_v @ LN1(p) + b_v) * ctx) + b_out
    k_fused<256, true><<<dim3(32, 4, 32), 256, 0, stream>>>(
        p, meanb, rstdb, g1, b1, wbase, bvv, ctxb,
        wbase + 65536, out_b + l * Dc, p);

    k_lnstats<false><<<512, 256, 0, stream>>>(p, nullptr, meanb, rstdb, nullptr);
    // fused FFN: p += W2 @ lrelu(W1 @ LN2(p) + b1) + b2
    k_fused<512, false><<<dim3(32, 4, 32), 256, 0, stream>>>(
        p, meanb, rstdb, g2, b2, wbase + 131072, f1_b + l * FFc, nullptr,
        wbase + 262144, f2_b + l * Dc, p);
  }

  k_lnstats<false><<<512, 256, 0, stream>>>(p, nullptr, meanb, rstdb, nullptr);
  k_bn2pre<<<1, 128, 0, stream>>>(bn2_g, bn2_b, bn2_m, bn2_v, bnscb, bnshb);
  // out = BN2(proj @ LNf(p)) fused with fold
  k_mm<256, 128, 256, 4096, true, S_LNF32, O_FOLDBN>
      <<<dim3(8, 4, 32), 256, 0, stream>>>(
      p, meanb, rstdb, lnf_g, lnf_b, wf_proj, nullptr, bnscb, bnshb, out);
}

// Round 2
// 779.998 us; speedup vs baseline: 1.2971x; 1.1801x over previous
//
#include <hip/hip_runtime.h>

// ---------------------------------------------------------------------------
// MobileViTBlockv2 — fused-chain bf16 MFMA version.
// B=32, C=128, H=W=64, D=256, FF=512, NL=2, PH=PW=2
// p: (B, D, 4, 1024) fp32. Attention chain (v->relu*ctx->out) and FFN chain
// (f1->lrelu->f2) each fused into ONE kernel: phase 1 builds the full
// intermediate for an n-col tile in LDS (MFMA B-fragment order), phase 2
// consumes it from LDS and accumulates into p.
//
// R1: 32-col tiles + double-buffered staging w/ register prefetch (occupancy
//     11->31%, FFN fused 217->150 us).
// R2: fuse next-LN stats (mean/rstd[/qdot]) into k_fused epilogue — each
//     block holds the full 256-row column of its 32 cols at store time, so
//     column stats are a shfl+LDS reduction away. Removes 4 of 5 k_lnstats
//     dispatches (each re-read all 134 MB of p). Stat buffers ping-pong.
// ---------------------------------------------------------------------------

typedef short  bh8 __attribute__((ext_vector_type(8)));   // 8 bf16 = 4 VGPR
typedef float  f4  __attribute__((ext_vector_type(4)));   // MFMA acc
typedef unsigned short us2 __attribute__((ext_vector_type(2)));
typedef unsigned short us4 __attribute__((ext_vector_type(4)));

constexpr int Bc = 32, Cc = 128, Dc = 256, FFc = 512;
constexpr int NNc = 1024, Sc = 4096;
constexpr float EPSc = 1e-5f;

enum SrcMode { S_LNF32, S_BF16 };
enum OutMode { O_STOREF32, O_FOLDBN };

__device__ __forceinline__ unsigned short f2bf(float f) {
  union { float f; unsigned int u; } v; v.f = f;
  unsigned int u = v.u + 0x7FFFu + ((v.u >> 16) & 1u);
  return (unsigned short)(u >> 16);
}

// ---- weight fp32 -> bf16 MFMA A-fragment order ----------------------------
// (m,k) -> ((kt*(M/16)+mt)*64 + lane)*8 + j ; lane=((k>>3)&3)<<4|(m&15), j=k&7
__global__ __launch_bounds__(256) void k_wconv(
    const float* __restrict__ w, unsigned short* __restrict__ dst,
    int total, int klog2)
{
  int idx = blockIdx.x * 256 + threadIdx.x;
  if (idx >= total) return;
  int K = 1 << klog2;
  int m = idx >> klog2, k = idx & (K - 1);
  int Mt = total >> klog2;
  size_t a = ((size_t)((k >> 5) * (Mt >> 4) + (m >> 4)) * 64
              + (((k >> 3) & 3) << 4) + (m & 15)) * 8 + (k & 7);
  dst[a] = f2bf(w[idx]);
}

// ---- dwconv 3x3 + BN1 + lrelu, 4 pixels/thread, bf16 patch layout ---------
__global__ __launch_bounds__(256) void k_dwconv(
    const float* __restrict__ x, const float* __restrict__ dww,
    const float* __restrict__ g, const float* __restrict__ bb,
    const float* __restrict__ mm, const float* __restrict__ vv,
    unsigned short* __restrict__ y1)
{
  int idx = blockIdx.x * 256 + threadIdx.x;   // (b,c,h,w4)
  int w4 = (idx & 15) * 4;
  int h  = (idx >> 4) & 63;
  int c  = (idx >> 10) & 127;
  int bi = idx >> 17;
  const float* xb = x + (size_t)(bi * 128 + c) * Sc;
  const float* wp = dww + c * 9;
  float acc[4] = {0.f, 0.f, 0.f, 0.f};
  #pragma unroll
  for (int kh = 0; kh < 3; ++kh) {
    int rr = h + kh - 1;
    if (rr < 0 || rr > 63) continue;
    const float* row = xb + rr * 64;
    float4 m4 = *reinterpret_cast<const float4*>(row + w4);
    float v[6];
    v[0] = (w4 > 0)  ? row[w4 - 1] : 0.f;
    v[1] = m4.x; v[2] = m4.y; v[3] = m4.z; v[4] = m4.w;
    v[5] = (w4 < 60) ? row[w4 + 4] : 0.f;
    float w0 = wp[kh * 3], w1 = wp[kh * 3 + 1], w2 = wp[kh * 3 + 2];
    #pragma unroll
    for (int o = 0; o < 4; ++o)
      acc[o] += w0 * v[o] + w1 * v[o + 1] + w2 * v[o + 2];
  }
  float sc = g[c] * rsqrtf(vv[c] + EPSc);
  float sh = bb[c] - mm[c] * sc;
  unsigned short r[4];
  #pragma unroll
  for (int o = 0; o < 4; ++o) {
    float val = acc[o] * sc + sh;
    r[o] = f2bf(val > 0.f ? val : 0.1f * val);
  }
  int ph = h & 1;
  size_t base = (size_t)(bi * 128 + c) * Sc + (h >> 1) * 32 + (w4 >> 1);
  *reinterpret_cast<us2*>(y1 + base + (ph * 2 + 0) * NNc) = (us2){r[0], r[2]};
  *reinterpret_cast<us2*>(y1 + base + (ph * 2 + 1) * NNc) = (us2){r[1], r[3]};
}

// ---- LN stats over D, optionally fused q-dot (only used once, after c1) ---
template<bool QD>
__global__ __launch_bounds__(256) void k_lnstats(
    const float* __restrict__ p, const float* __restrict__ wgq,
    float* __restrict__ mean_, float* __restrict__ rstd_, float* __restrict__ qdot)
{
  __shared__ float wg_s[256];
  int t = threadIdx.x;
  if (QD) { wg_s[t] = wgq[t]; __syncthreads(); }
  int pos = blockIdx.x * 256 + t;
  int b = pos >> 12, s = pos & 4095;
  const float* base = p + (size_t)b * Dc * Sc + s;
  float sum = 0.f, sq = 0.f, qa = 0.f;
  for (int d = 0; d < Dc; ++d) {
    float v = base[(size_t)d * Sc];
    sum += v; sq += v * v;
    if (QD) qa += v * wg_s[d];
  }
  float m   = sum * (1.f / Dc);
  float var = sq * (1.f / Dc) - m * m;
  mean_[pos] = m;
  rstd_[pos] = rsqrtf(fmaxf(var, 0.f) + EPSc);
  if (QD) qdot[pos] = qa;
}

// ---- per-layer prep: wgq = wq*g, s1 = sum(wq*g), s2 = sum(wq*b)+bq --------
__global__ void k_prep(const float* __restrict__ wq, const float* __restrict__ lng,
                       const float* __restrict__ lnb, const float* __restrict__ qb,
                       float* __restrict__ wgq, float* __restrict__ scal)
{
  int t = threadIdx.x, lane = t & 63, wv = t >> 6;
  float w = wq[t];
  float a = w * lng[t], c2 = w * lnb[t];
  wgq[t] = a;
  __shared__ float ra[4], rb[4];
  #pragma unroll
  for (int off = 32; off > 0; off >>= 1) { a += __shfl_xor(a, off); c2 += __shfl_xor(c2, off); }
  if (lane == 0) { ra[wv] = a; rb[wv] = c2; }
  __syncthreads();
  if (t == 0) {
    scal[0] = ra[0] + ra[1] + ra[2] + ra[3];
    scal[1] = rb[0] + rb[1] + rb[2] + rb[3] + qb[0];
  }
}

// ---- softmax over N from qdot/stats; emits u[n]=rs*s and U=sum(m*u) -------
__global__ __launch_bounds__(256) void k_softmax2(
    const float* __restrict__ qdot, const float* __restrict__ mean_,
    const float* __restrict__ rstd_, const float* __restrict__ scal,
    float* __restrict__ ub, float* __restrict__ Ub)
{
  int bp = blockIdx.x, b = bp >> 2, pp = bp & 3;
  int t = threadIdx.x, lane = t & 63, wv = t >> 6;
  __shared__ float r3[4], r4[4];
  float s1 = scal[0], s2 = scal[1];
  int pos0 = b * Sc + pp * NNc;
  float q[4], m_r[4], rs_r[4];
  float mx = -3.4e38f;
  #pragma unroll
  for (int i = 0; i < 4; ++i) {
    int pos = pos0 + t + i * 256;
    m_r[i] = mean_[pos]; rs_r[i] = rstd_[pos];
    q[i] = rs_r[i] * qdot[pos] - m_r[i] * rs_r[i] * s1 + s2;
    mx = fmaxf(mx, q[i]);
  }
  #pragma unroll
  for (int off = 32; off > 0; off >>= 1) mx = fmaxf(mx, __shfl_xor(mx, off));
  if (lane == 0) r3[wv] = mx;
  __syncthreads();
  mx = fmaxf(fmaxf(r3[0], r3[1]), fmaxf(r3[2], r3[3]));
  float sum = 0.f;
  #pragma unroll
  for (int i = 0; i < 4; ++i) { q[i] = __expf(q[i] - mx); sum += q[i]; }
  #pragma unroll
  for (int off = 32; off > 0; off >>= 1) sum += __shfl_xor(sum, off);
  if (lane == 0) r4[wv] = sum;
  __syncthreads();
  float inv = 1.f / (r4[0] + r4[1] + r4[2] + r4[3]);
  float pU = 0.f;
  #pragma unroll
  for (int i = 0; i < 4; ++i) {
    float un = rs_r[i] * q[i] * inv;
    ub[(size_t)bp * NNc + t + i * 256] = un;
    pU += m_r[i] * un;
  }
  #pragma unroll
  for (int off = 32; off > 0; off >>= 1) pU += __shfl_xor(pU, off);
  if (lane == 0) r3[wv] = pU;
  __syncthreads();
  if (t == 0) Ub[bp] = r3[0] + r3[1] + r3[2] + r3[3];
}

// ---- t_c = g_c*(sum_n p[c,n]*u[n] - U) + b_c ------------------------------
__global__ __launch_bounds__(256) void k_tpass(
    const float* __restrict__ p, const float* __restrict__ ub,
    const float* __restrict__ Ub, const float* __restrict__ lng,
    const float* __restrict__ lnb, float* __restrict__ tb)
{
  int cs = blockIdx.x, pp = blockIdx.y, b = blockIdx.z;
  int bp = b * 4 + pp;
  int t = threadIdx.x, lane = t & 63, wv = t >> 6;
  __shared__ float u_s[1024];
  for (int i = t; i < 1024; i += 256) u_s[i] = ub[(size_t)bp * NNc + i];
  __syncthreads();
  float U = Ub[bp];
  const float* pb = p + (size_t)b * Dc * Sc + pp * NNc;
  for (int i = 0; i < 16; ++i) {
    int c = cs * 64 + wv * 16 + i;
    const float* row = pb + (size_t)c * Sc;
    float sm = 0.f;
    #pragma unroll
    for (int j = 0; j < 16; ++j) { int n = lane + 64 * j; sm += row[n] * u_s[n]; }
    #pragma unroll
    for (int off = 32; off > 0; off >>= 1) sm += __shfl_xor(sm, off);
    if (lane == 0) tb[(size_t)bp * Dc + c] = lng[c] * (sm - U) + lnb[c];
  }
}

// ---- ctx[b,d,pp] = wk_row_d . t[b,pp,:] + bk_d ----------------------------
__global__ __launch_bounds__(256) void k_ctx2(
    const float* __restrict__ tb, const float* __restrict__ wk,
    const float* __restrict__ bk, float* __restrict__ ctxb)
{
  int b = blockIdx.x, d = threadIdx.x;
  __shared__ float ts[4][256];
  for (int i = threadIdx.x; i < 1024; i += 256) ts[i >> 8][i & 255] = tb[(size_t)b * 1024 + i];
  __syncthreads();
  const float* wrow = wk + (size_t)d * 256;
  float bkd = bk[d];
  float accp[4] = {0.f, 0.f, 0.f, 0.f};
  for (int c = 0; c < 256; c += 4) {
    float4 wv = *reinterpret_cast<const float4*>(wrow + c);
    #pragma unroll
    for (int pp = 0; pp < 4; ++pp)
      accp[pp] += wv.x * ts[pp][c] + wv.y * ts[pp][c + 1]
                + wv.z * ts[pp][c + 2] + wv.w * ts[pp][c + 3];
  }
  #pragma unroll
  for (int pp = 0; pp < 4; ++pp)
    ctxb[((size_t)(b * 256 + d)) * 4 + pp] = accp[pp] + bkd;
}

__global__ void k_bn2pre(const float* __restrict__ g, const float* __restrict__ bb,
                         const float* __restrict__ mm, const float* __restrict__ vv,
                         float* __restrict__ sc, float* __restrict__ sh)
{
  int c = threadIdx.x;
  if (c < Cc) {
    float s = g[c] * rsqrtf(vv[c] + EPSc);
    sc[c] = s;
    sh[c] = bb[c] - mm[c] * s;
  }
}

// ---------------------------------------------------------------------------
// Fused chain kernel: one (b, pp, 32-col n-tile) per block, 4 waves.
// Phase 1: I = act(W1 @ LN(p) + b1) [* ctx if ATTN], full M1 rows, K=256.
//          Double-buffered staging + register prefetch, one barrier/chunk.
// Phase 2: p += W2 @ I + b2   (M2=256, K=M1), I read from LDS.
// Epilogue: block holds the complete 256-row column of its 32 cols ->
//          compute next-LN mean/rstd (and optional q-dot) in-kernel.
// ---------------------------------------------------------------------------
template<int M1, bool ATTN, bool QDOT>
__global__ __launch_bounds__(256) void k_fused(
    const float* __restrict__ p,
    const float* __restrict__ mean_, const float* __restrict__ rstd_,
    const float* __restrict__ lng, const float* __restrict__ lnb,
    const unsigned short* __restrict__ wf1, const float* __restrict__ b1,
    const float* __restrict__ ctxp,
    const unsigned short* __restrict__ wf2, const float* __restrict__ b2,
    float* __restrict__ dst,
    const float* __restrict__ wgq2,
    float* __restrict__ mean_o, float* __restrict__ rstd_o,
    float* __restrict__ qdot_o)
{
  constexpr int NT = 32;                 // n-tile columns
  constexpr int NF = NT / 16;            // B fragments per tile (=2)
  constexpr int ACC1 = M1 / 64;          // row-tiles per wave, phase 1
  int t = threadIdx.x;
  int wv = t >> 6, lane = t & 63;
  int q = lane >> 4, ln16 = lane & 15;
  int nt = blockIdx.x, pp = blockIdx.y, b = blockIdx.z;
  int n0 = nt * NT;

  __shared__ unsigned int Alds[2][NT * 20];       // 5 KB double-buffered staging
  __shared__ unsigned short Frag[M1 * NT];        // intermediate, B-frag order
  __shared__ float m_s[NT], rs_s[NT];
  __shared__ float ctx_s[ATTN ? 256 : 4];

  // staging assignment: thread -> (k-pair kp_s, col-pair n2_s)
  int kp_s = t >> 4;            // 0..15
  int n2_s = (t & 15) * 2;      // 0,2,...,30

  size_t pbase = (size_t)b * Dc * Sc + pp * NNc + n0;

  // prefetch chunk 0 into registers (float2 = 8 B/lane, coalesced per k-row)
  float2 c0 = *reinterpret_cast<const float2*>(p + pbase + (size_t)(kp_s * 2) * Sc + n2_s);
  float2 c1 = *reinterpret_cast<const float2*>(p + pbase + (size_t)(kp_s * 2 + 1) * Sc + n2_s);

  if (t < NT) {
    int pos = b * Sc + pp * NNc + n0 + t;
    m_s[t]  = mean_[pos];
    rs_s[t] = rstd_[pos];
  }
  if (ATTN) ctx_s[t] = ctxp[(size_t)(b * Dc + t) * 4 + pp];

  f4 acc[ACC1][NF];
  #pragma unroll
  for (int i = 0; i < ACC1; ++i)
    #pragma unroll
    for (int j = 0; j < NF; ++j) acc[i][j] = (f4){0.f, 0.f, 0.f, 0.f};

  __syncthreads();   // m_s/rs_s (and ctx_s) ready

  // ---- phase 1: I = W1 @ LN(p), one barrier per K-chunk ----
  for (int kc = 0; kc < 256; kc += 32) {
    // LN + bf16-pack the chunk held in registers
    int k0 = kc + kp_s * 2;
    float g0 = lng[k0], g1 = lng[k0 + 1];
    float h0 = lnb[k0], h1 = lnb[k0 + 1];
    float ms0 = m_s[n2_s],     rs0 = rs_s[n2_s];
    float ms1 = m_s[n2_s + 1], rs1 = rs_s[n2_s + 1];
    float a00 = (c0.x - ms0) * rs0 * g0 + h0;   // (k0  , n2_s  )
    float a01 = (c0.y - ms1) * rs1 * g0 + h0;   // (k0  , n2_s+1)
    float a10 = (c1.x - ms0) * rs0 * g1 + h1;   // (k0+1, n2_s  )
    float a11 = (c1.y - ms1) * rs1 * g1 + h1;   // (k0+1, n2_s+1)
    unsigned int pk0 = (unsigned int)f2bf(a00) | ((unsigned int)f2bf(a10) << 16);
    unsigned int pk1 = (unsigned int)f2bf(a01) | ((unsigned int)f2bf(a11) << 16);

    // issue prefetch of next chunk (registers free after the pack above)
    if (kc < 224) {
      c0 = *reinterpret_cast<const float2*>(p + pbase + (size_t)(kc + 32 + kp_s * 2) * Sc + n2_s);
      c1 = *reinterpret_cast<const float2*>(p + pbase + (size_t)(kc + 32 + kp_s * 2 + 1) * Sc + n2_s);
    }

    unsigned int* alw = Alds[(kc >> 5) & 1];
    alw[n2_s * 20 + kp_s]       = pk0;
    alw[(n2_s + 1) * 20 + kp_s] = pk1;

    bh8 aw[ACC1];
    #pragma unroll
    for (int tm = 0; tm < ACC1; ++tm)
      aw[tm] = *(const bh8*)(wf1 + ((size_t)((kc >> 5) * (M1 >> 4) + wv * ACC1 + tm) * 64 + lane) * 8);

    __syncthreads();   // stage of this chunk visible; dbuf makes 2nd barrier unnecessary

    const unsigned short* al = (const unsigned short*)Alds[(kc >> 5) & 1];
    #pragma unroll
    for (int tn = 0; tn < NF; ++tn) {
      bh8 bwf = *(const bh8*)(al + (tn * 16 + ln16) * 40 + q * 8);
      #pragma unroll
      for (int tm = 0; tm < ACC1; ++tm)
        acc[tm][tn] = __builtin_amdgcn_mfma_f32_16x16x32_bf16(aw[tm], bwf, acc[tm][tn], 0, 0, 0);
    }
  }

  // ---- phase 1 epilogue: act + write Frag (B-frag order) ----
  #pragma unroll
  for (int tm = 0; tm < ACC1; ++tm) {
    int row0 = wv * (M1 / 4) + tm * 16 + q * 4;
    float bia[4], cxv[4];
    #pragma unroll
    for (int r = 0; r < 4; ++r) {
      bia[r] = b1[row0 + r];
      if (ATTN) cxv[r] = ctx_s[row0 + r];
    }
    int kt  = row0 >> 5;
    int sub = (row0 >> 3) & 3;
    int jo  = row0 & 7;
    #pragma unroll
    for (int tn = 0; tn < NF; ++tn) {
      int cl = tn * 16 + ln16;
      us4 pk;
      #pragma unroll
      for (int r = 0; r < 4; ++r) {
        float v = acc[tm][tn][r] + bia[r];
        if (ATTN) v = fmaxf(v, 0.f) * cxv[r];
        else      v = v > 0.f ? v : 0.1f * v;
        pk[r] = f2bf(v);
      }
      *reinterpret_cast<us4*>(Frag + (((kt * NF + (cl >> 4)) * 64 + (sub << 4 | (cl & 15))) * 8 + jo)) = pk;
    }
  }
  __syncthreads();

  // ---- phase 2: p += W2 @ I ----
  f4 acc2[4][NF];
  #pragma unroll
  for (int i = 0; i < 4; ++i)
    #pragma unroll
    for (int j = 0; j < NF; ++j) acc2[i][j] = (f4){0.f, 0.f, 0.f, 0.f};

  for (int kc = 0; kc < M1; kc += 32) {
    bh8 aw2[4];
    #pragma unroll
    for (int tm = 0; tm < 4; ++tm)
      aw2[tm] = *(const bh8*)(wf2 + ((size_t)((kc >> 5) * 16 + wv * 4 + tm) * 64 + lane) * 8);
    #pragma unroll
    for (int tn = 0; tn < NF; ++tn) {
      bh8 bwf = *(const bh8*)(Frag + ((kc >> 5) * NF + tn) * 512 + lane * 8);
      #pragma unroll
      for (int tm = 0; tm < 4; ++tm)
        acc2[tm][tn] = __builtin_amdgcn_mfma_f32_16x16x32_bf16(aw2[tm], bwf, acc2[tm][tn], 0, 0, 0);
    }
  }

  // ---- phase 2 epilogue: residual add + store + next-LN stats ----
  float s1[NF], s2[NF], s3[NF];
  #pragma unroll
  for (int tn = 0; tn < NF; ++tn) { s1[tn] = 0.f; s2[tn] = 0.f; s3[tn] = 0.f; }
  #pragma unroll
  for (int tm = 0; tm < 4; ++tm) {
    #pragma unroll
    for (int r = 0; r < 4; ++r) {
      int row = wv * 64 + tm * 16 + q * 4 + r;
      float bv = b2[row];
      float wqr = QDOT ? wgq2[row] : 0.f;
      #pragma unroll
      for (int tn = 0; tn < NF; ++tn) {
        int col = n0 + tn * 16 + ln16;
        size_t da = (size_t)(b * Dc + row) * Sc + pp * NNc + col;
        float v = dst[da] + acc2[tm][tn][r] + bv;
        dst[da] = v;
        s1[tn] += v; s2[tn] += v * v;
        if (QDOT) s3[tn] += v * wqr;
      }
    }
  }
  // reduce over q (lane bits 4,5): each wave covers 64 rows of the column
  #pragma unroll
  for (int tn = 0; tn < NF; ++tn) {
    s1[tn] += __shfl_xor(s1[tn], 16); s1[tn] += __shfl_xor(s1[tn], 32);
    s2[tn] += __shfl_xor(s2[tn], 16); s2[tn] += __shfl_xor(s2[tn], 32);
    if (QDOT) { s3[tn] += __shfl_xor(s3[tn], 16); s3[tn] += __shfl_xor(s3[tn], 32); }
  }
  __syncthreads();               // all waves done reading Frag
  float* fr = (float*)Frag;      // reuse: [wv][3][NT]
  if (q == 0) {
    #pragma unroll
    for (int tn = 0; tn < NF; ++tn) {
      int col = tn * 16 + ln16;
      fr[(wv * 3 + 0) * NT + col] = s1[tn];
      fr[(wv * 3 + 1) * NT + col] = s2[tn];
      fr[(wv * 3 + 2) * NT + col] = s3[tn];
    }
  }
  __syncthreads();
  if (t < NT) {
    float a1 = 0.f, a2 = 0.f, a3 = 0.f;
    #pragma unroll
    for (int w2 = 0; w2 < 4; ++w2) {
      a1 += fr[(w2 * 3 + 0) * NT + t];
      a2 += fr[(w2 * 3 + 1) * NT + t];
      a3 += fr[(w2 * 3 + 2) * NT + t];
    }
    int pos = b * Sc + pp * NNc + n0 + t;
    float mn  = a1 * (1.f / 256.f);
    float var = a2 * (1.f / 256.f) - mn * mn;
    mean_o[pos] = mn;
    rstd_o[pos] = rsqrtf(fmaxf(var, 0.f) + EPSc);
    if (QDOT) qdot_o[pos] = a3;
  }
}

// ---------------------------------------------------------------------------
// Standalone MFMA GEMM (used for c1 and proj).
// ---------------------------------------------------------------------------
template<int KTOT, int MTOT, int SRCCH, int SSTR, bool SPP,
         SrcMode SM, OutMode OM>
__global__ __launch_bounds__(256) void k_mm(
    const void* __restrict__ src,
    const float* __restrict__ mean_, const float* __restrict__ rstd_,
    const float* __restrict__ lng, const float* __restrict__ lnb,
    const unsigned short* __restrict__ wf, const float* __restrict__ bias,
    const float* __restrict__ bnsc, const float* __restrict__ bnsh,
    void* __restrict__ dst)
{
  int t = threadIdx.x;
  int wv = t >> 6, lane = t & 63;
  int wm = wv & 1, wn = wv >> 1;
  int q = lane >> 4, ln16 = lane & 15;
  int nb = blockIdx.x, b = blockIdx.z;
  int pp = blockIdx.y & 3, mb = blockIdx.y >> 2;
  int n0  = nb * 128;
  int MB0 = mb * 128;

  __shared__ unsigned int Alds[128 * 20];
  __shared__ float m_s[128], rs_s[128];

  if (SM == S_LNF32 && t < 128) {
    int pos = b * Sc + pp * NNc + n0 + t;
    m_s[t]  = mean_[pos];
    rs_s[t] = rstd_[pos];
  }

  f4 acc[4][4];
  #pragma unroll
  for (int i = 0; i < 4; ++i)
    #pragma unroll
    for (int j = 0; j < 4; ++j) acc[i][j] = (f4){0.f, 0.f, 0.f, 0.f};

  size_t sbase = (size_t)b * SRCCH * SSTR + pp * NNc + n0;
  int mtb = (MB0 >> 4) + wm * 4;

  for (int kc = 0; kc < KTOT; kc += 32) {
    bh8 aw[4];
    #pragma unroll
    for (int tm = 0; tm < 4; ++tm)
      aw[tm] = *(const bh8*)(wf + ((size_t)((kc >> 5) * (MTOT >> 4) + mtb + tm) * 64 + lane) * 8);
    __syncthreads();
    #pragma unroll
    for (int it = 0; it < 8; ++it) {
      int n_l = (t & 63) + (it & 1) * 64;
      int kp  = (t >> 6) + (it >> 1) * 4;
      int k0  = kc + kp * 2;
      unsigned int pk;
      if (SM == S_LNF32) {
        const float* sp = (const float*)src;
        float a0 = sp[sbase + (size_t)k0 * SSTR + n_l];
        float a1 = sp[sbase + (size_t)(k0 + 1) * SSTR + n_l];
        float ms = m_s[n_l], rs = rs_s[n_l];
        a0 = (a0 - ms) * rs * lng[k0] + lnb[k0];
        a1 = (a1 - ms) * rs * lng[k0 + 1] + lnb[k0 + 1];
        pk = (unsigned int)f2bf(a0) | ((unsigned int)f2bf(a1) << 16);
      } else {
        const unsigned short* sp = (const unsigned short*)src;
        unsigned int u0 = sp[sbase + (size_t)k0 * SSTR + n_l];
        unsigned int u1 = sp[sbase + (size_t)(k0 + 1) * SSTR + n_l];
        pk = u0 | (u1 << 16);
      }
      Alds[n_l * 20 + kp] = pk;
    }
    __syncthreads();
    const unsigned short* al = (const unsigned short*)Alds;
    #pragma unroll
    for (int tn = 0; tn < 4; ++tn) {
      int nrow = wn * 64 + tn * 16 + ln16;
      bh8 bwf = *(const bh8*)(al + nrow * 40 + q * 8);
      #pragma unroll
      for (int tm = 0; tm < 4; ++tm)
        acc[tm][tn] = __builtin_amdgcn_mfma_f32_16x16x32_bf16(aw[tm], bwf, acc[tm][tn], 0, 0, 0);
    }
  }

  #pragma unroll
  for (int tm = 0; tm < 4; ++tm) {
    #pragma unroll
    for (int r = 0; r < 4; ++r) {
      int row = MB0 + wm * 64 + tm * 16 + q * 4 + r;
      float scv = 0.f, shv = 0.f, bv = 0.f;
      if (OM == O_FOLDBN) { scv = bnsc[row]; shv = bnsh[row]; }
      else                { bv = bias[row]; }
      #pragma unroll
      for (int tn = 0; tn < 4; ++tn) {
        int col = n0 + wn * 64 + tn * 16 + ln16;
        float v = acc[tm][tn][r];
        if (OM == O_FOLDBN) {
          int hh = 2 * (col >> 5) + (pp >> 1), ww = 2 * (col & 31) + (pp & 1);
          ((float*)dst)[((size_t)(b * Cc + row)) * Sc + hh * 64 + ww] = v * scv + shv;
        } else {
          ((float*)dst)[(size_t)(b * MTOT + row) * Sc + pp * NNc + col] = v + bv;
        }
      }
    }
  }
}

// ---------------------------------------------------------------------------
extern "C" void kernel_launch(void* const* d_in, const int* in_sizes, int n_in,
                              void* d_out, int out_size, void* d_ws, size_t ws_size,
                              hipStream_t stream)
{
  const float* x     = (const float*)d_in[0];
  const float* dw_w  = (const float*)d_in[1];
  const float* bn1_g = (const float*)d_in[2];
  const float* bn1_b = (const float*)d_in[3];
  const float* bn1_m = (const float*)d_in[4];
  const float* bn1_v = (const float*)d_in[5];
  const float* c1_w  = (const float*)d_in[6];
  const float* c1_b  = (const float*)d_in[7];
  const float* ln1_g = (const float*)d_in[8];
  const float* ln1_b = (const float*)d_in[9];
  const float* qkv_w = (const float*)d_in[10];
  const float* qkv_b = (const float*)d_in[11];
  const float* out_w = (const float*)d_in[12];
  const float* out_b = (const float*)d_in[13];
  const float* ln2_g = (const float*)d_in[14];
  const float* ln2_b = (const float*)d_in[15];
  const float* f1_w  = (const float*)d_in[16];
  const float* f1_b  = (const float*)d_in[17];
  const float* f2_w  = (const float*)d_in[18];
  const float* f2_b  = (const float*)d_in[19];
  const float* lnf_g = (const float*)d_in[20];
  const float* lnf_b = (const float*)d_in[21];
  const float* projw = (const float*)d_in[22];
  const float* bn2_g = (const float*)d_in[23];
  const float* bn2_b = (const float*)d_in[24];
  const float* bn2_m = (const float*)d_in[25];
  const float* bn2_v = (const float*)d_in[26];
  float* out = (float*)d_out;

  // ---- workspace ----
  float* ws    = (float*)d_ws;
  float* p     = ws;                                       // 33,554,432 f
  float* reg   = p + (size_t)33554432;                     // 8,388,608 f (y1 bf16)
  unsigned short* y1u = (unsigned short*)reg;
  // reg region is dead after c1 k_mm -> reuse for ping-pong stat set B
  float* mean2 = reg;                                      // 131072 f
  float* rstd2 = reg + 131072;                             // 131072 f
  float* meanb = reg   + (size_t)8388608;
  float* rstdb = meanb + 131072;
  float* qdotb = rstdb + 131072;
  float* ub    = qdotb + 131072;
  float* Ub    = ub    + 131072;                           // 128
  float* tb    = Ub    + 128;                              // 32768
  float* ctxb  = tb    + 32768;                            // 32768
  float* wgq   = ctxb  + 32768;                            // 512 (2 layers)
  float* scal  = wgq   + 512;                              // 16
  float* bnscb = scal  + 16;                               // 128
  float* bnshb = bnscb + 128;                              // 128
  unsigned short* wfb = (unsigned short*)(bnshb + 128);
  unsigned short* wf_c1   = wfb;                           // 32768
  unsigned short* wf_v0   = wfb + 32768;                   // per-l stride 393216
  unsigned short* wf_proj = wfb + 32768 + 2 * 393216;      // 32768

  // ---- weight conversion ----
  k_wconv<<<128, 256, 0, stream>>>(c1_w, wf_c1, 256 * 128, 7);
  for (int l = 0; l < 2; ++l) {
    const float* wvp = qkv_w + ((size_t)l * 513 + 257) * Dc;
    unsigned short* base = wf_v0 + (size_t)l * 393216;
    k_wconv<<<256, 256, 0, stream>>>(wvp, base, 256 * 256, 8);
    k_wconv<<<256, 256, 0, stream>>>(out_w + (size_t)l * Dc * Dc, base + 65536, 256 * 256, 8);
    k_wconv<<<512, 256, 0, stream>>>(f1_w + (size_t)l * FFc * Dc, base + 131072, 512 * 256, 8);
    k_wconv<<<512, 256, 0, stream>>>(f2_w + (size_t)l * Dc * FFc, base + 262144, 256 * 512, 9);
  }
  k_wconv<<<128, 256, 0, stream>>>(projw, wf_proj, 128 * 256, 8);

  // ---- per-layer LN1/q prep, both layers upfront ----
  for (int l = 0; l < 2; ++l)
    k_prep<<<1, 256, 0, stream>>>(qkv_w + (size_t)l * 513 * Dc,
                                  ln1_g + l * Dc, ln1_b + l * Dc,
                                  qkv_b + l * 513, wgq + l * 256, scal + l * 2);

  // ---- 1) dwconv + BN1 + lrelu -> y1 bf16 (patch layout) ----
  k_dwconv<<<16384, 256, 0, stream>>>(x, dw_w, bn1_g, bn1_b, bn1_m, bn1_v, y1u);

  // ---- 2) c1: p = W_c1 @ y1 + b ----
  k_mm<128, 256, 128, 4096, true, S_BF16, O_STOREF32>
      <<<dim3(8, 8, 32), 256, 0, stream>>>(
      y1u, nullptr, nullptr, nullptr, nullptr, wf_c1, c1_b, nullptr, nullptr, p);

  // ln1 stats + qdot for layer 0 (the only standalone stats pass left)
  k_lnstats<true><<<512, 256, 0, stream>>>(p, wgq, meanb, rstdb, qdotb);

  for (int l = 0; l < 2; ++l) {
    const float* g1 = ln1_g + l * Dc; const float* b1 = ln1_b + l * Dc;
    const float* g2 = ln2_g + l * Dc; const float* b2 = ln2_b + l * Dc;
    const float* wk = qkv_w + ((size_t)l * 513 + 1) * Dc;
    const float* bk = qkv_b + l * 513 + 1;
    const float* bvv = qkv_b + l * 513 + 257;
    unsigned short* wbase = wf_v0 + (size_t)l * 393216;

    k_softmax2<<<128, 256, 0, stream>>>(qdotb, meanb, rstdb, scal + l * 2, ub, Ub);
    k_tpass<<<dim3(4, 4, 32), 256, 0, stream>>>(p, ub, Ub, g1, b1, tb);
    k_ctx2<<<32, 256, 0, stream>>>(tb, wk, bk, ctxb);

    // fused attention: p += W_out @ (relu(W_v @ LN1(p) + b_v) * ctx) + b_out
    // epilogue -> LN2 stats into set B
    k_fused<256, true, false><<<dim3(32, 4, 32), 256, 0, stream>>>(
        p, meanb, rstdb, g1, b1, wbase, bvv, ctxb,
        wbase + 65536, out_b + l * Dc, p,
        nullptr, mean2, rstd2, nullptr);

    // fused FFN: p += W2 @ lrelu(W1 @ LN2(p) + b1) + b2
    // epilogue -> next LN1 (l=0: +qdot for layer 1) or LNf (l=1) into set A
    if (l == 0) {
      k_fused<512, false, true><<<dim3(32, 4, 32), 256, 0, stream>>>(
          p, mean2, rstd2, g2, b2, wbase + 131072, f1_b + l * FFc, nullptr,
          wbase + 262144, f2_b + l * Dc, p,
          wgq + 256, meanb, rstdb, qdotb);
    } else {
      k_fused<512, false, false><<<dim3(32, 4, 32), 256, 0, stream>>>(
          p, mean2, rstd2, g2, b2, wbase + 131072, f1_b + l * FFc, nullptr,
          wbase + 262144, f2_b + l * Dc, p,
          nullptr, meanb, rstdb, nullptr);
    }
  }

  k_bn2pre<<<1, 128, 0, stream>>>(bn2_g, bn2_b, bn2_m, bn2_v, bnscb, bnshb);
  // out = BN2(proj @ LNf(p)) fused with fold; LNf stats came from last FFN epilogue
  k_mm<256, 128, 256, 4096, true, S_LNF32, O_FOLDBN>
      <<<dim3(8, 4, 32), 256, 0, stream>>>(
      p, meanb, rstdb, lnf_g, lnf_b, wf_proj, nullptr, bnscb, bnshb, out);
}